// Round 3
// baseline (90.365 us; speedup 1.0000x reference)
//
#include <hip/hip_runtime.h>
#include <stdint.h>

typedef unsigned long long u64;

#define N_ANCH (32768 * 8)
#define N_CLS 80
#define TOPK 200
#define CAP 4096
#define NBINS 256
#define BIN_BASE 16064u   // 0x3EC0: (bits>>16) of floats ~>=0.375; valid scores (>0.4) land in bins [12,192]
#define SCORE_T 0.4f
#define NMS_T 0.4f

// ---- workspace layout (byte offsets) ----
#define OFF_SCORES 0
#define OFF_CLS    (N_ANCH * 4)
#define OFF_HIST   (N_ANCH * 5)
#define OFF_CNT    (OFF_HIST + NBINS * 4)
#define OFF_CIDX   (OFF_CNT + 16)
#define OFF_CSC    (OFF_CIDX + CAP * 4)
#define OFF_CCLS   (OFF_CSC + CAP * 4)

// Kernel 0: zero hist + cnt. Replaces hipMemsetAsync — the graph-captured
// memset node executed as a ~48us fillBufferAligned dispatch (R2 profile);
// a 1-block kernel does the same 1040B in ~2us.
__global__ __launch_bounds__(256) void k_zero(unsigned* __restrict__ hist,
                                              unsigned* __restrict__ cnt) {
  hist[threadIdx.x] = 0u;
  if (threadIdx.x < 4) cnt[threadIdx.x] = 0u;
}

// Kernel 1: per-anchor score = max_c(conf*prob[c]) AND argmax class (first-max
// wins, matching jnp.argmax); write score-or--1 + class u8; histogram top-16
// float bits of valid scores. Memory-bound: reads ~85MB.
__global__ __launch_bounds__(256) void k_score(
    const float* __restrict__ conf, const float* __restrict__ prob,
    float* __restrict__ scores, unsigned char* __restrict__ cls8,
    unsigned* __restrict__ hist) {
  __shared__ unsigned lh[NBINS];
  const int t = threadIdx.x;
  lh[t] = 0;  // blockDim == NBINS == 256
  __syncthreads();

  const int i = blockIdx.x * 256 + t;
  const float c = conf[i];
  const float4* p = (const float4*)(prob + (size_t)i * N_CLS);
  float best = -1.0f;
  int bidx = 0;
#pragma unroll
  for (int k = 0; k < N_CLS / 4; ++k) {
    float4 v = p[k];
    const float s0 = c * v.x, s1 = c * v.y, s2 = c * v.z, s3 = c * v.w;
    if (s0 > best) { best = s0; bidx = 4 * k; }
    if (s1 > best) { best = s1; bidx = 4 * k + 1; }
    if (s2 > best) { best = s2; bidx = 4 * k + 2; }
    if (s3 > best) { best = s3; bidx = 4 * k + 3; }
  }
  const float s = (best > SCORE_T) ? best : -1.0f;
  scores[i] = s;
  cls8[i] = (unsigned char)bidx;
  if (s > SCORE_T) {
    unsigned b = (__float_as_uint(s) >> 16) - BIN_BASE;
    b = b > 255u ? 255u : b;
    atomicAdd(&lh[b], 1u);
  }
  __syncthreads();
  if (lh[t]) atomicAdd(&hist[t], lh[t]);
}

// Kernel 2: per-block suffix-scan of histogram (cheap, redundant) to find the
// exact key threshold covering >= TOPK items, then compact candidates
// (idx, score, class). float4 score reads: 256 blocks.
__global__ __launch_bounds__(256) void k_compact(
    const float* __restrict__ scores, const unsigned char* __restrict__ cls8,
    const unsigned* __restrict__ hist, unsigned* __restrict__ cnt,
    unsigned* __restrict__ cidx, float* __restrict__ csc,
    unsigned char* __restrict__ ccls) {
  __shared__ unsigned suf[NBINS];
  __shared__ unsigned s_lo;
  const int t = threadIdx.x;
  suf[t] = hist[t];
  __syncthreads();
  // Hillis-Steele suffix sum: suf[t] = count of valid scores with bin >= t
  for (int d = 1; d < NBINS; d <<= 1) {
    unsigned v = (t + d < NBINS) ? suf[t + d] : 0u;
    __syncthreads();
    suf[t] += v;
    __syncthreads();
  }
  if (t == 0 && suf[0] < TOPK) s_lo = 0u;  // fewer than TOPK valid: take all
  if (suf[t] >= TOPK && (t == NBINS - 1 || suf[t + 1] < TOPK))
    s_lo = (t + BIN_BASE) << 16;
  __syncthreads();

  const unsigned lo = s_lo;
  const int i4 = blockIdx.x * 256 + t;
  const float4 s4 = ((const float4*)scores)[i4];
#pragma unroll
  for (int k = 0; k < 4; ++k) {
    const float s = (k == 0) ? s4.x : (k == 1) ? s4.y : (k == 2) ? s4.z : s4.w;
    const int i = i4 * 4 + k;
    if (s > SCORE_T && __float_as_uint(s) >= lo) {
      unsigned pos = atomicAdd(cnt, 1u);
      if (pos < CAP) {
        cidx[pos] = (unsigned)i;
        csc[pos] = s;
        ccls[pos] = cls8[i];
      }
    }
  }
}

// Kernel 3 (single block): exact top-200 (rank-by-counting on (scoreBits,~idx)
// keys -> matches lax.top_k tie semantics), decode boxes for winners, IoU
// adjacency bitmasks (uniform-j broadcast reads), BRANCHLESS unrolled greedy
// NMS, stable-compacted output. All hot loops have compile-time-unrollable
// shapes so LDS reads pipeline instead of serializing on lgkmcnt.
__global__ __launch_bounds__(512) void k_final(
    const float* __restrict__ pred, const float* __restrict__ priors,
    const float* __restrict__ img, const unsigned* __restrict__ cnt,
    const unsigned* __restrict__ cidx, const float* __restrict__ csc,
    const unsigned char* __restrict__ ccls, float* __restrict__ out) {
  __shared__ u64 kb[CAP];
  __shared__ unsigned ti[TOPK];
  __shared__ float tsc[TOPK];
  __shared__ float tcl[TOPK];
  __shared__ float4 bxv[TOPK];
  __shared__ float ar[TOPK];
  __shared__ u64 adj[TOPK][4];
  __shared__ u64 kw[4];
  __shared__ int s_cnt;

  const int t = threadIdx.x;
  const unsigned m = *cnt;
  const int M = (int)(m < (unsigned)CAP ? m : (unsigned)CAP);
  const int Mpad = (M + 7) & ~7;
  const int Kp = M < TOPK ? M : TOPK;

  for (int i = t; i < Mpad; i += 512) {
    // pad keys are 0 (< any valid key: score bits >= 0x3ECCCCCD)
    kb[i] = (i < M) ? (((u64)__float_as_uint(csc[i]) << 32) |
                       (unsigned)(~cidx[i]))
                    : 0ull;
  }
  if (t < TOPK) {  // init rows >= Kp so IoU reads are defined
    bxv[t] = make_float4(0.f, 0.f, 0.f, 0.f);
    ar[t] = 0.f;
  }
  __syncthreads();

  // rank-by-counting: rank(e) = #{j : key_j > key_e}; keys unique (idx embedded)
  for (int e = t; e < M; e += 512) {
    const u64 ke = kb[e];
    int r = 0;
#pragma unroll 8
    for (int j = 0; j < Mpad; ++j) r += (kb[j] > ke);
    if (r < TOPK) {
      ti[r] = ~(unsigned)kb[e];
      tsc[r] = __uint_as_float((unsigned)(ke >> 32));
      tcl[r] = (float)ccls[e];
    }
  }
  __syncthreads();

  if (t < Kp) {
    const unsigned idx = ti[t];
    const float4 pd = ((const float4*)pred)[idx];
    const float4 pr = ((const float4*)priors)[idx];
    const float4 im = *(const float4*)img;
    const float x = pd.x + pr.x, y = pd.y + pr.y;
    const float w = pd.z * pr.z, h = pd.w * pr.w;
    const float x1 = ((x - 0.5f * w) / 30.0f) * im.x;
    const float y1 = ((y - 0.5f * h) / 10.0f) * im.y;
    const float x2 = ((x + 0.5f * w) / 30.0f) * im.z;
    const float y2 = ((y + 0.5f * h) / 10.0f) * im.w;
    bxv[t] = make_float4(x1, y1, x2, y2);
    ar[t] = (x2 - x1) * (y2 - y1);
  }
  __syncthreads();

  // IoU adjacency: j is wave-uniform (broadcast LDS reads, conflict-free);
  // outer wq loop fully unrolled so the accumulator word stays in registers.
  if (t < TOPK) {
    const float4 bt = bxv[t];
    const float a = ar[t];
    u64 w0 = 0, w1 = 0, w2 = 0, w3 = 0;
#pragma unroll
    for (int wq = 0; wq < 4; ++wq) {
      const int jmax = (wq == 3) ? (TOPK - 192) : 64;
      u64 wv = 0;
#pragma unroll 8
      for (int jj = 0; jj < jmax; ++jj) {
        const int j = wq * 64 + jj;
        const float4 bj = bxv[j];
        const float aj = ar[j];
        const float xx1 = fmaxf(bt.x, bj.x);
        const float yy1 = fmaxf(bt.y, bj.y);
        const float xx2 = fminf(bt.z, bj.z);
        const float yy2 = fminf(bt.w, bj.w);
        const float inter = fmaxf(xx2 - xx1, 0.0f) * fmaxf(yy2 - yy1, 0.0f);
        const float iou = inter / (a + aj - inter);
        const bool sup = (iou > NMS_T) & (j > t) & (j < Kp);
        wv |= (u64)sup << jj;
      }
      if (wq == 0) w0 = wv;
      else if (wq == 1) w1 = wv;
      else if (wq == 2) w2 = wv;
      else w3 = wv;
    }
    adj[t][0] = w0; adj[t][1] = w1; adj[t][2] = w2; adj[t][3] = w3;
  }
  __syncthreads();

  // Branchless greedy: adjacency reads don't depend on keep state ->
  // unroll-8 keeps 16 ds_read_b128 in flight; chain is ~10 VALU/iter.
  if (t == 0) {
    auto initw = [&](int w) -> u64 {
      const int lo = w * 64;
      if (Kp <= lo) return 0ull;
      const int n = Kp - lo;
      return n >= 64 ? ~0ull : ((1ull << n) - 1ull);
    };
    u64 k0 = initw(0), k1 = initw(1), k2 = initw(2), k3 = initw(3);
#pragma unroll 8
    for (int i = 0; i < TOPK; ++i) {
      const u64 r0 = adj[i][0], r1 = adj[i][1], r2 = adj[i][2], r3 = adj[i][3];
      const u64 kwv = (i < 64) ? k0 : (i < 128) ? k1 : (i < 192) ? k2 : k3;
      const u64 msk = 0ull - ((kwv >> (i & 63)) & 1ull);  // ~0 if kept else 0
      k0 &= ~(r0 & msk);
      k1 &= ~(r1 & msk);
      k2 &= ~(r2 & msk);
      k3 &= ~(r3 & msk);
    }
    kw[0] = k0; kw[1] = k1; kw[2] = k2; kw[3] = k3;
    s_cnt = __popcll(k0) + __popcll(k1) + __popcll(k2) + __popcll(k3);
  }
  __syncthreads();

  const int count = s_cnt;
  if (t < TOPK) {
    const bool kept = (t < Kp) && ((kw[t >> 6] >> (t & 63)) & 1ull);
    if (kept) {
      int pos = 0;
      for (int w = 0; w < (t >> 6); ++w) pos += __popcll(kw[w]);
      pos += __popcll(kw[t >> 6] & ((1ull << (t & 63)) - 1ull));
      out[pos * 4 + 0] = bxv[t].x;
      out[pos * 4 + 1] = bxv[t].y;
      out[pos * 4 + 2] = bxv[t].z;
      out[pos * 4 + 3] = bxv[t].w;
      out[800 + pos] = tsc[t];
      out[1000 + pos] = tcl[t];
    }
    if (t >= count) {
      out[t * 4 + 0] = 0.0f;
      out[t * 4 + 1] = 0.0f;
      out[t * 4 + 2] = 0.0f;
      out[t * 4 + 3] = 0.0f;
      out[800 + t] = 0.0f;
      out[1000 + t] = -1.0f;
    }
  }
  if (t == 0) out[1200] = (float)count;
}

extern "C" void kernel_launch(void* const* d_in, const int* in_sizes, int n_in,
                              void* d_out, int out_size, void* d_ws,
                              size_t ws_size, hipStream_t stream) {
  const float* pred   = (const float*)d_in[0];
  const float* conf   = (const float*)d_in[1];
  const float* prob   = (const float*)d_in[2];
  const float* priors = (const float*)d_in[3];
  const float* img    = (const float*)d_in[4];
  float* out = (float*)d_out;

  char* ws = (char*)d_ws;
  float* scores        = (float*)(ws + OFF_SCORES);
  unsigned char* cls8  = (unsigned char*)(ws + OFF_CLS);
  unsigned* hist       = (unsigned*)(ws + OFF_HIST);
  unsigned* cnt        = (unsigned*)(ws + OFF_CNT);
  unsigned* cidx       = (unsigned*)(ws + OFF_CIDX);
  float* csc           = (float*)(ws + OFF_CSC);
  unsigned char* ccls  = (unsigned char*)(ws + OFF_CCLS);

  k_zero<<<1, 256, 0, stream>>>(hist, cnt);
  k_score<<<N_ANCH / 256, 256, 0, stream>>>(conf, prob, scores, cls8, hist);
  k_compact<<<N_ANCH / 1024, 256, 0, stream>>>(scores, cls8, hist, cnt, cidx,
                                               csc, ccls);
  k_final<<<1, 512, 0, stream>>>(pred, priors, img, cnt, cidx, csc, ccls, out);
}

// Round 4
// 80.487 us; speedup vs baseline: 1.1227x; 1.1227x over previous
//
#include <hip/hip_runtime.h>
#include <stdint.h>

typedef unsigned long long u64;

#define N_ANCH (32768 * 8)
#define N_CLS 80
#define TOPK 200
#define CAP 4096
#define NBINS2 4096
#define BASE12 0x3ECCCu   // (0x3ECCCCCD>>12): scores>0.4 have (bits>>12) >= this
#define SCORE_T 0.4f
#define NMS_T 0.4f

// ---- workspace layout (byte offsets) ----
#define OFF_SCORES 0
#define OFF_CLS    (N_ANCH * 4)
#define OFF_HIST   (N_ANCH * 5)
#define OFF_CNT    (OFF_HIST + NBINS2 * 4)
#define OFF_CIDX   (OFF_CNT + 16)
#define OFF_CSC    (OFF_CIDX + CAP * 4)
#define OFF_CCLS   (OFF_CSC + CAP * 4)

// Kernel 0: zero hist (4096 bins) + cnt/thr words.
__global__ __launch_bounds__(1024) void k_zero(uint4* __restrict__ hist4,
                                               unsigned* __restrict__ cnt) {
  hist4[threadIdx.x] = make_uint4(0u, 0u, 0u, 0u);
  if (threadIdx.x < 4) cnt[threadIdx.x] = 0u;
}

// Kernel 1: QUAD-PER-ANCHOR score/argmax. 4 lanes share one anchor (20 classes
// each, contiguous 80B per lane -> 4x fewer VMEM instrs, 64B-contiguous quads
// vs 320B lane stride). Exact semantics: per-class c*p products (no conf
// factoring), first-max ties via u64 (scoreBits<<32 | 255-cls) max-reduce.
// Histogram: direct global atomics over 4096 sparse bins (bits>>12).
__global__ __launch_bounds__(256) void k_score(
    const float* __restrict__ conf, const float* __restrict__ prob,
    float* __restrict__ scores, unsigned char* __restrict__ cls8,
    unsigned* __restrict__ hist) {
  const int l = threadIdx.x;
  const int g = l >> 2, q = l & 3;           // 64 anchors per block
  const int a = blockIdx.x * 64 + g;
  const float c = conf[a];
  const float4* p = (const float4*)(prob + (size_t)a * N_CLS + q * 20);
  float best = -1.0f;
  int bcls = 0;
#pragma unroll
  for (int k = 0; k < 5; ++k) {
    const float4 v = p[k];
    const int cb = q * 20 + k * 4;
    const float s0 = c * v.x, s1 = c * v.y, s2 = c * v.z, s3 = c * v.w;
    if (s0 > best) { best = s0; bcls = cb; }
    if (s1 > best) { best = s1; bcls = cb + 1; }
    if (s2 > best) { best = s2; bcls = cb + 2; }
    if (s3 > best) { best = s3; bcls = cb + 3; }
  }
  // best >= 0 after first product (c,p >= 0) -> float order == u32 bit order
  u64 key = ((u64)__float_as_uint(best) << 32) | (unsigned)(255 - bcls);
  const u64 o1 = __shfl_xor(key, 1, 4); key = key > o1 ? key : o1;
  const u64 o2 = __shfl_xor(key, 2, 4); key = key > o2 ? key : o2;
  if (q == 0) {
    const float s = __uint_as_float((unsigned)(key >> 32));
    const int cls = 255 - (int)(key & 0xFFu);
    const bool valid = s > SCORE_T;
    scores[a] = valid ? s : -1.0f;   // 16 lanes/wave write 64B contiguous
    cls8[a] = (unsigned char)cls;
    if (valid) {
      unsigned bin = (__float_as_uint(s) >> 12) - BASE12;
      bin = bin > (NBINS2 - 1u) ? (NBINS2 - 1u) : bin;
      atomicAdd(&hist[bin], 1u);
    }
  }
}

// Kernel 1.5 (1 block): suffix-scan 4096 bins, find max bin b with
// count(>=b) >= TOPK; write bit-threshold to thr (=cnt[1]). Boundary bin now
// holds ~100 items -> M ~ 310 candidates instead of ~1100.
__global__ __launch_bounds__(1024) void k_thresh(
    const uint4* __restrict__ hist4, unsigned* __restrict__ thr) {
  __shared__ unsigned suf[1024];
  const int t = threadIdx.x;
  const uint4 h = hist4[t];
  suf[t] = h.x + h.y + h.z + h.w;
  __syncthreads();
  for (int d = 1; d < 1024; d <<= 1) {
    const unsigned v = (t + d < 1024) ? suf[t + d] : 0u;
    __syncthreads();
    suf[t] += v;
    __syncthreads();
  }
  const unsigned after = (t < 1023) ? suf[t + 1] : 0u;
  const unsigned cg3 = h.w + after, cg2 = h.z + cg3, cg1 = h.y + cg2,
                 cg0 = h.x + cg1;
  if (cg0 >= TOPK && cg1 < TOPK) thr[0] = ((unsigned)(4 * t + 0) + BASE12) << 12;
  if (cg1 >= TOPK && cg2 < TOPK) thr[0] = ((unsigned)(4 * t + 1) + BASE12) << 12;
  if (cg2 >= TOPK && cg3 < TOPK) thr[0] = ((unsigned)(4 * t + 2) + BASE12) << 12;
  if (cg3 >= TOPK && after < TOPK) thr[0] = ((unsigned)(4 * t + 3) + BASE12) << 12;
  if (t == 0 && cg0 < TOPK) thr[0] = 0u;  // fewer than TOPK valid: take all
}

// Kernel 2: compact candidates >= threshold (append order irrelevant: k_final
// totally orders by (score,idx)).
__global__ __launch_bounds__(256) void k_compact(
    const float* __restrict__ scores, const unsigned char* __restrict__ cls8,
    const unsigned* __restrict__ thr, unsigned* __restrict__ cnt,
    unsigned* __restrict__ cidx, float* __restrict__ csc,
    unsigned char* __restrict__ ccls) {
  const unsigned lo = thr[0];
  const int i4 = blockIdx.x * 256 + threadIdx.x;
  const float4 s4 = ((const float4*)scores)[i4];
#pragma unroll
  for (int k = 0; k < 4; ++k) {
    const float s = (k == 0) ? s4.x : (k == 1) ? s4.y : (k == 2) ? s4.z : s4.w;
    const int i = i4 * 4 + k;
    if (s > SCORE_T && __float_as_uint(s) >= lo) {
      const unsigned pos = atomicAdd(cnt, 1u);
      if (pos < CAP) {
        cidx[pos] = (unsigned)i;
        csc[pos] = s;
        ccls[pos] = cls8[i];
      }
    }
  }
}

// Kernel 3 (single block): exact top-200 (rank-by-counting on (scoreBits,~idx)
// keys -> lax.top_k tie semantics), box decode, IoU adjacency bitmasks
// (uniform-j broadcast LDS reads), branchless unrolled greedy NMS,
// stable-compacted output. Classes/count stored as float.
__global__ __launch_bounds__(512) void k_final(
    const float* __restrict__ pred, const float* __restrict__ priors,
    const float* __restrict__ img, const unsigned* __restrict__ cnt,
    const unsigned* __restrict__ cidx, const float* __restrict__ csc,
    const unsigned char* __restrict__ ccls, float* __restrict__ out) {
  __shared__ u64 kb[CAP];
  __shared__ unsigned ti[TOPK];
  __shared__ float tsc[TOPK];
  __shared__ float tcl[TOPK];
  __shared__ float4 bxv[TOPK];
  __shared__ float ar[TOPK];
  __shared__ u64 adj[TOPK][4];
  __shared__ u64 kw[4];
  __shared__ int s_cnt;

  const int t = threadIdx.x;
  const unsigned m = *cnt;
  const int M = (int)(m < (unsigned)CAP ? m : (unsigned)CAP);
  const int Mpad = (M + 7) & ~7;
  const int Kp = M < TOPK ? M : TOPK;

  for (int i = t; i < Mpad; i += 512) {
    // pad keys are 0 (< any valid key: score bits >= 0x3ECCCCCE)
    kb[i] = (i < M) ? (((u64)__float_as_uint(csc[i]) << 32) |
                       (unsigned)(~cidx[i]))
                    : 0ull;
  }
  if (t < TOPK) {  // init rows >= Kp so IoU reads are defined
    bxv[t] = make_float4(0.f, 0.f, 0.f, 0.f);
    ar[t] = 0.f;
  }
  __syncthreads();

  // rank-by-counting: rank(e) = #{j : key_j > key_e}; keys unique (idx embedded)
  for (int e = t; e < M; e += 512) {
    const u64 ke = kb[e];
    int r = 0;
#pragma unroll 8
    for (int j = 0; j < Mpad; ++j) r += (kb[j] > ke);
    if (r < TOPK) {
      ti[r] = ~(unsigned)ke;
      tsc[r] = __uint_as_float((unsigned)(ke >> 32));
      tcl[r] = (float)ccls[e];
    }
  }
  __syncthreads();

  if (t < Kp) {
    const unsigned idx = ti[t];
    const float4 pd = ((const float4*)pred)[idx];
    const float4 pr = ((const float4*)priors)[idx];
    const float4 im = *(const float4*)img;
    const float x = pd.x + pr.x, y = pd.y + pr.y;
    const float w = pd.z * pr.z, h = pd.w * pr.w;
    const float x1 = ((x - 0.5f * w) / 30.0f) * im.x;
    const float y1 = ((y - 0.5f * h) / 10.0f) * im.y;
    const float x2 = ((x + 0.5f * w) / 30.0f) * im.z;
    const float y2 = ((y + 0.5f * h) / 10.0f) * im.w;
    bxv[t] = make_float4(x1, y1, x2, y2);
    ar[t] = (x2 - x1) * (y2 - y1);
  }
  __syncthreads();

  // IoU adjacency: j wave-uniform -> broadcast LDS reads, conflict-free.
  if (t < TOPK) {
    const float4 bt = bxv[t];
    const float a = ar[t];
    u64 w0 = 0, w1 = 0, w2 = 0, w3 = 0;
#pragma unroll
    for (int wq = 0; wq < 4; ++wq) {
      const int jmax = (wq == 3) ? (TOPK - 192) : 64;
      u64 wv = 0;
#pragma unroll 8
      for (int jj = 0; jj < jmax; ++jj) {
        const int j = wq * 64 + jj;
        const float4 bj = bxv[j];
        const float aj = ar[j];
        const float xx1 = fmaxf(bt.x, bj.x);
        const float yy1 = fmaxf(bt.y, bj.y);
        const float xx2 = fminf(bt.z, bj.z);
        const float yy2 = fminf(bt.w, bj.w);
        const float inter = fmaxf(xx2 - xx1, 0.0f) * fmaxf(yy2 - yy1, 0.0f);
        const float iou = inter / (a + aj - inter);
        const bool sup = (iou > NMS_T) & (j > t) & (j < Kp);
        wv |= (u64)sup << jj;
      }
      if (wq == 0) w0 = wv;
      else if (wq == 1) w1 = wv;
      else if (wq == 2) w2 = wv;
      else w3 = wv;
    }
    adj[t][0] = w0; adj[t][1] = w1; adj[t][2] = w2; adj[t][3] = w3;
  }
  __syncthreads();

  // Branchless greedy: adjacency reads independent of keep state -> pipelined.
  if (t == 0) {
    auto initw = [&](int w) -> u64 {
      const int lo = w * 64;
      if (Kp <= lo) return 0ull;
      const int n = Kp - lo;
      return n >= 64 ? ~0ull : ((1ull << n) - 1ull);
    };
    u64 k0 = initw(0), k1 = initw(1), k2 = initw(2), k3 = initw(3);
#pragma unroll 8
    for (int i = 0; i < TOPK; ++i) {
      const u64 r0 = adj[i][0], r1 = adj[i][1], r2 = adj[i][2], r3 = adj[i][3];
      const u64 kwv = (i < 64) ? k0 : (i < 128) ? k1 : (i < 192) ? k2 : k3;
      const u64 msk = 0ull - ((kwv >> (i & 63)) & 1ull);
      k0 &= ~(r0 & msk);
      k1 &= ~(r1 & msk);
      k2 &= ~(r2 & msk);
      k3 &= ~(r3 & msk);
    }
    kw[0] = k0; kw[1] = k1; kw[2] = k2; kw[3] = k3;
    s_cnt = __popcll(k0) + __popcll(k1) + __popcll(k2) + __popcll(k3);
  }
  __syncthreads();

  const int count = s_cnt;
  if (t < TOPK) {
    const bool kept = (t < Kp) && ((kw[t >> 6] >> (t & 63)) & 1ull);
    if (kept) {
      int pos = 0;
      for (int w = 0; w < (t >> 6); ++w) pos += __popcll(kw[w]);
      pos += __popcll(kw[t >> 6] & ((1ull << (t & 63)) - 1ull));
      out[pos * 4 + 0] = bxv[t].x;
      out[pos * 4 + 1] = bxv[t].y;
      out[pos * 4 + 2] = bxv[t].z;
      out[pos * 4 + 3] = bxv[t].w;
      out[800 + pos] = tsc[t];
      out[1000 + pos] = tcl[t];
    }
    if (t >= count) {
      out[t * 4 + 0] = 0.0f;
      out[t * 4 + 1] = 0.0f;
      out[t * 4 + 2] = 0.0f;
      out[t * 4 + 3] = 0.0f;
      out[800 + t] = 0.0f;
      out[1000 + t] = -1.0f;
    }
  }
  if (t == 0) out[1200] = (float)count;
}

extern "C" void kernel_launch(void* const* d_in, const int* in_sizes, int n_in,
                              void* d_out, int out_size, void* d_ws,
                              size_t ws_size, hipStream_t stream) {
  const float* pred   = (const float*)d_in[0];
  const float* conf   = (const float*)d_in[1];
  const float* prob   = (const float*)d_in[2];
  const float* priors = (const float*)d_in[3];
  const float* img    = (const float*)d_in[4];
  float* out = (float*)d_out;

  char* ws = (char*)d_ws;
  float* scores        = (float*)(ws + OFF_SCORES);
  unsigned char* cls8  = (unsigned char*)(ws + OFF_CLS);
  unsigned* hist       = (unsigned*)(ws + OFF_HIST);
  unsigned* cnt        = (unsigned*)(ws + OFF_CNT);   // [0]=counter [1]=thr
  unsigned* cidx       = (unsigned*)(ws + OFF_CIDX);
  float* csc           = (float*)(ws + OFF_CSC);
  unsigned char* ccls  = (unsigned char*)(ws + OFF_CCLS);

  k_zero<<<1, 1024, 0, stream>>>((uint4*)hist, cnt);
  k_score<<<N_ANCH / 64, 256, 0, stream>>>(conf, prob, scores, cls8, hist);
  k_thresh<<<1, 1024, 0, stream>>>((const uint4*)hist, cnt + 1);
  k_compact<<<N_ANCH / 1024, 256, 0, stream>>>(scores, cls8, cnt + 1, cnt,
                                               cidx, csc, ccls);
  k_final<<<1, 512, 0, stream>>>(pred, priors, img, cnt, cidx, csc, ccls, out);
}